// Round 11
// baseline (657.044 us; speedup 1.0000x reference)
//
#include <hip/hip_runtime.h>

// Problem constants (B, L, H, D) = (4, 4096, 8, 64), FACTOR=5
#define NB 4
#define LSEQ 4096
#define NH 8
#define ND 64
#define NSAMP 45
#define NTOP 45
#define ACH 256            // keys per attention chunk
#define NCH (LSEQ / ACH)   // 16 chunks

typedef float f32x4 __attribute__((ext_vector_type(4)));

// ===========================================================================
// r15/r16: LAUNCH-COUNT REDUCTION. Fit across rounds 5-9: total = sum(kernel
// times) + N_launches * ~30us. 8 launches = ~240us of the 415-473us totals.
// Fuse to 3:
//   KA = prep U cumsumA (+ zero counters)
//   KB = compute_M (round-7 body, bit-identical M) + inline last-block topk
//   KC = attn_partial U cumsumC + last-block merge + second-finisher scatter
// Cross-block sync: last/second-finisher pattern ONLY (release fence +
// device atomic; acquire fence after). NO spin-waits anywhere -> deadlock
// structurally impossible, dispatch-order independent (G16-safe). Counters
// re-zeroed every invocation (graph-replay safe). r16 = r15 resubmit after
// infra container failure; kernel audit found no hang hazard.
// Fallback tiers if ws_size too small: round-7 8-kernel path, then attn_rows.
// ===========================================================================

// ---------------------------------------------------------------------------
// KA: blocks 0..15 = prep (bucket-sort (idx,s) by chunk; r10 semantics);
//     blocks 16..527 = cumsumA. Block 0 also zeroes the 576 counter ints.
// ---------------------------------------------------------------------------
__global__ __launch_bounds__(256) void fusedA_kernel(
        const int* __restrict__ idxS, int* __restrict__ sortedPack,
        const float* __restrict__ V, float* __restrict__ chunkSums,
        int* __restrict__ cnts) {
    int blk = blockIdx.x;
    int t = threadIdx.x;
    __shared__ int cnt[256][17];
    __shared__ float part[4][ND];

    if (blk < 16) {
        if (blk == 0) {
            for (int i = t; i < 576; i += 256) cnts[i] = 0;
        }
        int l = blk * 256 + t;
        const int* is = idxS + (size_t)l * NSAMP;
        #pragma unroll
        for (int c = 0; c < 16; ++c) cnt[t][c] = 0;
        for (int s = 0; s < NSAMP; ++s) cnt[t][is[s] >> 8] += 1;
        int run = 0;
        #pragma unroll
        for (int c = 0; c < 16; ++c) { int v = cnt[t][c]; cnt[t][c] = run; run += v; }
        for (int s = 0; s < NSAMP; ++s) {
            int idx = is[s];
            int pos = cnt[t][idx >> 8]++;
            sortedPack[(size_t)l * NSAMP + pos] = (idx << 8) | s;
        }
    } else {
        int blk2 = blk - 16;
        int c = blk2 & 15;
        int bh = blk2 >> 4;
        int h = bh & (NH - 1);
        int b = bh >> 3;
        int g = t >> 6, d = t & 63;

        const size_t rstride = (size_t)NH * ND;
        size_t vbase = (size_t)b * LSEQ * rstride + (size_t)h * ND + d;

        int l0 = c * 256 + g * 64;
        float s = 0.0f;
        for (int l = l0; l < l0 + 64; ++l) s += V[vbase + (size_t)l * rstride];

        part[g][d] = s;
        __syncthreads();
        if (t < ND)
            chunkSums[(size_t)blk2 * ND + d] =
                part[0][d] + part[1][d] + part[2][d] + part[3][d];
    }
}

// ---------------------------------------------------------------------------
// KB: compute_M — ROUND-7 BODY VERBATIM (107us best; LDS-staged K chunks,
// Plds parked dots, ORIGINAL-s-order fold -> M bit-identical -> selection
// frozen). Appended: inline topk by the last-finishing block of each bh
// (8 blocks/bh). Selection semantics identical to topk_kernel: per-iteration
// global (max value, min index) winner, winner masked. doTopk=0 -> plain
// compute_M (used by fallback tier).
// ---------------------------------------------------------------------------
__global__ __launch_bounds__(512, 1) void fusedM_kernel(
        const float* __restrict__ Q,
        const float* __restrict__ K,
        const int* __restrict__ sortedPack,
        float* __restrict__ Mout,
        int* __restrict__ Mtop,
        int* __restrict__ cntM,
        int doTopk) {
    int xcd = blockIdx.x & 7;
    int sub = blockIdx.x >> 3;
    int bh  = (xcd << 2) | (sub & 3);      // 4 bh per XCD -> 4MB L2 K stream
    int lt  = sub >> 2;                    // 0..7 (512-l tile)
    int b = bh >> 3, h = bh & 7;
    int t = threadIdx.x;                   // 0..511
    int l0 = (lt << 9) + t;

    __shared__ float Ks[256 * 68];
    __shared__ float Plds[512 * 45];
    __shared__ float wv[8];
    __shared__ int   wi[8];
    __shared__ int   winIdx;
    __shared__ int   amLast;

    f32x4 qa[16];
    {
        const f32x4* qp0 = reinterpret_cast<const f32x4*>(
            Q + (((size_t)b * LSEQ + l0) * NH + h) * ND);
        #pragma unroll
        for (int i = 0; i < 16; ++i) qa[i] = __builtin_nontemporal_load(qp0 + i);
    }

    auto dotQK = [&](const f32x4 (&q4)[16], const float* kr) -> float {
        const f32x4* k4 = reinterpret_cast<const f32x4*>(kr);
        float w[32];
        #pragma unroll
        for (int i = 0; i < 8; ++i) {
            f32x4 a = q4[i], bb = k4[i], c = q4[i + 8], d4 = k4[i + 8];
            w[4 * i + 0] = __fadd_rn(__fmul_rn(a.x, bb.x), __fmul_rn(c.x, d4.x));
            w[4 * i + 1] = __fadd_rn(__fmul_rn(a.y, bb.y), __fmul_rn(c.y, d4.y));
            w[4 * i + 2] = __fadd_rn(__fmul_rn(a.z, bb.z), __fmul_rn(c.z, d4.z));
            w[4 * i + 3] = __fadd_rn(__fmul_rn(a.w, bb.w), __fmul_rn(c.w, d4.w));
        }
        #pragma unroll
        for (int off = 16; off; off >>= 1) {
            #pragma unroll
            for (int i = 0; i < off; ++i) w[i] = __fadd_rn(w[i], w[i + off]);
        }
        return w[0];
    };

    const int* sp0 = sortedPack + (size_t)l0 * NSAMP;
    int ptr0 = 0;
    int pk0 = sp0[0];

    size_t kbh = ((size_t)b * LSEQ * NH + h) * ND;

    for (int c = 0; c < 16; ++c) {
        #pragma unroll
        for (int i = 0; i < 8; ++i) {
            int flat = i * 512 + t;
            int row = flat >> 4, col = flat & 15;
            f32x4 v = *reinterpret_cast<const f32x4*>(
                K + kbh + (size_t)(c * 256 + row) * (NH * ND) + col * 4);
            *reinterpret_cast<f32x4*>(&Ks[row * 68 + col * 4]) = v;
        }
        __syncthreads();

        while ((pk0 >> 16) == c) {
            int r = (pk0 >> 8) & 255;
            int s = pk0 & 255;
            Plds[t * 45 + s] = dotQK(qa, &Ks[r * 68]);
            ++ptr0;
            pk0 = (ptr0 < NSAMP) ? sp0[ptr0] : 0x7fffffff;
        }
        __syncthreads();
    }

    {
        float maxv = -INFINITY, sumv = 0.0f;
        for (int s = 0; s < NSAMP; ++s) {
            float v = Plds[t * 45 + s];
            maxv = fmaxf(maxv, v);
            sumv = __fadd_rn(sumv, v);
        }
        Mout[(size_t)bh * LSEQ + l0] = maxv - sumv * (1.0f / (float)LSEQ);
    }

    if (!doTopk) return;

    // ---- inline last-block-per-bh topk (no spin; last finisher proceeds) ----
    __threadfence();                 // release own M stores (device scope)
    __syncthreads();                 // all threads' fences done
    if (t == 0) amLast = (atomicAdd(&cntM[bh], 1) == 7);
    __syncthreads();
    if (!amLast) return;
    __threadfence();                 // acquire side

    const float* m = Mout + (size_t)bh * LSEQ;
    float rv[8];
    #pragma unroll
    for (int k = 0; k < 8; ++k) rv[k] = m[t + (k << 9)];

    int wave = t >> 6, lane = t & 63;
    for (int iter = 0; iter < NTOP; ++iter) {
        float bv = -INFINITY; int bi = 0x7fffffff;
        #pragma unroll
        for (int k = 0; k < 8; ++k) {
            float v = rv[k];
            if (v > bv) { bv = v; bi = t + (k << 9); }
        }
        #pragma unroll
        for (int off = 1; off < 64; off <<= 1) {
            float ov = __shfl_xor(bv, off, 64);
            int   oi = __shfl_xor(bi, off, 64);
            if (ov > bv || (ov == bv && oi < bi)) { bv = ov; bi = oi; }
        }
        if (lane == 0) { wv[wave] = bv; wi[wave] = bi; }
        __syncthreads();
        if (t == 0) {
            float cv = wv[0]; int ci = wi[0];
            for (int ww = 1; ww < 8; ++ww) {
                if (wv[ww] > cv || (wv[ww] == cv && wi[ww] < ci)) { cv = wv[ww]; ci = wi[ww]; }
            }
            winIdx = ci;
            Mtop[bh * NTOP + iter] = ci;
        }
        __syncthreads();
        int widx = winIdx;
        #pragma unroll
        for (int k = 0; k < 8; ++k)
            if (widx == t + (k << 9)) rv[k] = -INFINITY;
        __syncthreads();
    }
}

// ---------------------------------------------------------------------------
// KC: blocks 0..511 = attn_partial (r11 body) + last-block-per-bh merge;
//     blocks 512..1023 = cumsumC. Scatter of the 1440 attention rows is done
//     per (bh,chunk) by WHICHEVER of {merge block, cumsumC block} finishes
//     second (paired atomic counter cnt2[bh*16+c]; exactly one sees old==1).
//     Release fence before each increment, acquire fence after -> scatter
//     writes are globally ordered after both cumsumC's row writes and
//     merge's ctx writes. No spin-waits.
// ---------------------------------------------------------------------------
__global__ __launch_bounds__(256, 1) void fusedC_kernel(
        const float* __restrict__ Q, const float* __restrict__ K,
        const float* __restrict__ V, const int* __restrict__ Mtop,
        float* __restrict__ part, const float* __restrict__ chunkSums,
        float* __restrict__ ctx, float* __restrict__ out,
        int* __restrict__ cntA, int* __restrict__ cnt2) {
    int blk = blockIdx.x;
    int t = threadIdx.x;

    __shared__ float Qs[NTOP * ND];
    __shared__ int   posS[NTOP];
    __shared__ float Vs[64][68];
    __shared__ float Pw[4][64];
    __shared__ float cpart[4][ND];
    __shared__ int   flagA;
    __shared__ unsigned int scatMask;

    if (blk < 512) {
        // ---------------- attn_partial ----------------
        int bh = blk >> 4;
        int c  = blk & 15;
        int b = bh >> 3, h = bh & 7;
        int w = t >> 6, lane = t & 63;
        int jj = lane >> 4, dq = lane & 15;

        size_t base = ((size_t)b * LSEQ * NH + h) * ND;

        if (t < NTOP) posS[t] = Mtop[bh * NTOP + t];
        __syncthreads();
        for (int idx = t; idx < NTOP * 16; idx += 256) {
            int u = idx >> 4, cg = idx & 15;
            f32x4 v = *reinterpret_cast<const f32x4*>(
                Q + base + (size_t)posS[u] * (NH * ND) + cg * 4);
            *reinterpret_cast<f32x4*>(&Qs[u * ND + cg * 4]) = v;
        }

        f32x4 o[12];
        float mreg[12], sreg[12];
        #pragma unroll
        for (int qi = 0; qi < 12; ++qi) {
            o[qi] = 0.0f; mreg[qi] = -INFINITY; sreg[qi] = 0.0f;
        }

        for (int tt = 0; tt < ACH / 64; ++tt) {
            int tile0 = c * ACH + tt * 64;
            __syncthreads();
            #pragma unroll
            for (int i = 0; i < 4; ++i) {
                int flat = i * 256 + t;
                int r = flat >> 4, cg = flat & 15;
                f32x4 v = *reinterpret_cast<const f32x4*>(
                    V + base + (size_t)(tile0 + r) * (NH * ND) + cg * 4);
                *reinterpret_cast<f32x4*>(&Vs[r][cg * 4]) = v;
            }
            __syncthreads();

            f32x4 kreg[16];
            #pragma unroll
            for (int i = 0; i < 16; ++i)
                kreg[i] = *reinterpret_cast<const f32x4*>(
                    K + base + (size_t)(tile0 + lane) * (NH * ND) + i * 4);

            #pragma unroll
            for (int qi = 0; qi < 12; ++qi) {
                int u = w + 4 * qi;
                if (u >= NTOP) continue;
                int pu = posS[u];
                if (pu < tile0) continue;

                float a0 = 0, a1 = 0, a2 = 0, a3 = 0;
                #pragma unroll
                for (int di = 0; di < 16; ++di) {
                    f32x4 qv = *reinterpret_cast<const f32x4*>(&Qs[u * ND + di * 4]);
                    a0 = fmaf(qv.x, kreg[di].x, a0);
                    a1 = fmaf(qv.y, kreg[di].y, a1);
                    a2 = fmaf(qv.z, kreg[di].z, a2);
                    a3 = fmaf(qv.w, kreg[di].w, a3);
                }
                float sc = ((a0 + a1) + (a2 + a3)) * 0.125f;
                if (tile0 + lane > pu) sc = -INFINITY;

                float tmax = sc;
                #pragma unroll
                for (int off = 1; off < 64; off <<= 1)
                    tmax = fmaxf(tmax, __shfl_xor(tmax, off, 64));
                float mold = mreg[qi];
                float mnew = fmaxf(mold, tmax);
                float alpha = __expf(mold - mnew);
                float e = __expf(sc - mnew);
                float esum = e;
                #pragma unroll
                for (int off = 1; off < 64; off <<= 1)
                    esum += __shfl_xor(esum, off, 64);
                sreg[qi] = sreg[qi] * alpha + esum;
                mreg[qi] = mnew;
                Pw[w][lane] = e;
                o[qi] *= alpha;
                #pragma unroll
                for (int i = 0; i < 16; ++i) {
                    float pe = Pw[w][i * 4 + jj];
                    f32x4 vv = *reinterpret_cast<const f32x4*>(&Vs[i * 4 + jj][dq * 4]);
                    o[qi] += vv * pe;
                }
            }
        }

        #pragma unroll
        for (int qi = 0; qi < 12; ++qi) {
            int u = w + 4 * qi;
            if (u >= NTOP) continue;
            if (posS[u] < c * ACH) continue;
            f32x4 oo = o[qi];
            #pragma unroll
            for (int off = 16; off <= 32; off <<= 1) {
                oo.x += __shfl_xor(oo.x, off, 64);
                oo.y += __shfl_xor(oo.y, off, 64);
                oo.z += __shfl_xor(oo.z, off, 64);
                oo.w += __shfl_xor(oo.w, off, 64);
            }
            size_t pb = ((size_t)(bh * NTOP + u) * NCH + c) * 72;
            if (lane < 16)
                *reinterpret_cast<f32x4*>(&part[pb + 4 + dq * 4]) = oo;
            if (lane == 0) { part[pb] = mreg[qi]; part[pb + 1] = sreg[qi]; }
        }

        // ---- last block of this bh: merge partials -> ctx ----
        __threadfence();
        __syncthreads();
        if (t == 0) flagA = (atomicAdd(&cntA[bh], 1) == 15);
        __syncthreads();
        if (!flagA) return;
        __threadfence();

        for (int u = w; u < NTOP; u += 4) {
            int pos = posS[u];
            int cmax = pos >> 8;
            size_t pb0 = (size_t)(bh * NTOP + u) * NCH * 72;
            float mm = -INFINITY;
            for (int cc = 0; cc <= cmax; ++cc)
                mm = fmaxf(mm, part[pb0 + (size_t)cc * 72]);
            float S = 0.0f, oacc = 0.0f;
            for (int cc = 0; cc <= cmax; ++cc) {
                float mc = part[pb0 + (size_t)cc * 72];
                float sc = part[pb0 + (size_t)cc * 72 + 1];
                float wgt = __expf(mc - mm);
                S = fmaf(sc, wgt, S);
                oacc = fmaf(part[pb0 + (size_t)cc * 72 + 4 + lane], wgt, oacc);
            }
            ctx[(size_t)(bh * NTOP + u) * ND + lane] = oacc / S;
        }

        // ---- claim scatter for chunks whose cumsumC already finished ----
        __threadfence();
        __syncthreads();
        if (t == 0) {
            unsigned int mask = 0;
            for (int cc = 0; cc < 16; ++cc)
                if (atomicAdd(&cnt2[bh * 16 + cc], 1) == 1) mask |= (1u << cc);
            scatMask = mask;
        }
        __syncthreads();
        unsigned int mask = scatMask;
        if (mask) {
            __threadfence();
            for (int idx = t; idx < NTOP * ND; idx += 256) {
                int u = idx >> 6, d = idx & 63;
                int pos = Mtop[bh * NTOP + u];
                if (mask & (1u << (pos >> 8)))
                    out[((size_t)bh * LSEQ + pos) * ND + d] =
                        ctx[(size_t)(bh * NTOP + u) * ND + d];
            }
        }
    } else {
        // ---------------- cumsumC ----------------
        int blk2 = blk - 512;
        int c = blk2 & 15;
        int bh = blk2 >> 4;
        int h = bh & (NH - 1);
        int b = bh >> 3;
        int g = t >> 6, d = t & 63;

        const size_t rstride = (size_t)NH * ND;
        size_t vbase = (size_t)b * LSEQ * rstride + (size_t)h * ND + d;

        float run = 0.0f;
        for (int cc = 0; cc < c; ++cc)
            run += chunkSums[((size_t)bh * 16 + cc) * ND + d];

        int l0 = c * 256 + g * 64;
        float s = 0.0f;
        for (int l = l0; l < l0 + 64; ++l) s += V[vbase + (size_t)l * rstride];
        cpart[g][d] = s;
        __syncthreads();
        for (int gg = 0; gg < g; ++gg) run += cpart[gg][d];

        size_t obase = (size_t)bh * LSEQ * ND + d;
        for (int l = l0; l < l0 + 64; ++l) {
            run += V[vbase + (size_t)l * rstride];
            out[obase + (size_t)l * ND] = run;
        }

        // ---- if merge already published ctx for this bh: scatter chunk c ----
        __threadfence();
        __syncthreads();
        if (t == 0) flagA = (atomicAdd(&cnt2[bh * 16 + c], 1) == 1);
        __syncthreads();
        if (!flagA) return;
        __threadfence();
        for (int idx = t; idx < NTOP * ND; idx += 256) {
            int u = idx >> 6, d2 = idx & 63;
            int pos = Mtop[bh * NTOP + u];
            if ((pos >> 8) == c)
                out[((size_t)bh * LSEQ + pos) * ND + d2] =
                    ctx[(size_t)(bh * NTOP + u) * ND + d2];
        }
    }
}

// ===========================================================================
// Fallback-tier kernels (round-7 path, unchanged semantics).
// ===========================================================================
__global__ __launch_bounds__(256) void prep_kernel(
        const int* __restrict__ idxS, int* __restrict__ sortedPack) {
    int t = threadIdx.x;
    int l = blockIdx.x * 256 + t;
    const int* is = idxS + (size_t)l * NSAMP;
    __shared__ int cnt[256][17];
    #pragma unroll
    for (int c = 0; c < 16; ++c) cnt[t][c] = 0;
    for (int s = 0; s < NSAMP; ++s) cnt[t][is[s] >> 8] += 1;
    int run = 0;
    #pragma unroll
    for (int c = 0; c < 16; ++c) { int v = cnt[t][c]; cnt[t][c] = run; run += v; }
    for (int s = 0; s < NSAMP; ++s) {
        int idx = is[s];
        int pos = cnt[t][idx >> 8]++;
        sortedPack[(size_t)l * NSAMP + pos] = (idx << 8) | s;
    }
}

__global__ __launch_bounds__(256) void topk_kernel(
        const float* __restrict__ M, int* __restrict__ Mtop) {
    int bh = blockIdx.x;
    int t = threadIdx.x;
    int wave = t >> 6, lane = t & 63;
    const float* m = M + (size_t)bh * LSEQ;

    float rv[16];
    #pragma unroll
    for (int k = 0; k < 16; ++k) rv[k] = m[t + (k << 8)];

    __shared__ float wv[4];
    __shared__ int   wi[4];
    __shared__ int   winIdx;

    for (int iter = 0; iter < NTOP; ++iter) {
        float bv = -INFINITY; int bi = 0x7fffffff;
        #pragma unroll
        for (int k = 0; k < 16; ++k) {
            float v = rv[k];
            if (v > bv) { bv = v; bi = t + (k << 8); }
        }
        #pragma unroll
        for (int off = 1; off < 64; off <<= 1) {
            float ov = __shfl_xor(bv, off, 64);
            int   oi = __shfl_xor(bi, off, 64);
            if (ov > bv || (ov == bv && oi < bi)) { bv = ov; bi = oi; }
        }
        if (lane == 0) { wv[wave] = bv; wi[wave] = bi; }
        __syncthreads();
        if (t == 0) {
            float cv = wv[0]; int ci = wi[0];
            for (int ww = 1; ww < 4; ++ww) {
                if (wv[ww] > cv || (wv[ww] == cv && wi[ww] < ci)) { cv = wv[ww]; ci = wi[ww]; }
            }
            winIdx = ci;
            Mtop[bh * NTOP + iter] = ci;
        }
        __syncthreads();
        int widx = winIdx;
        #pragma unroll
        for (int k = 0; k < 16; ++k)
            if (widx == t + (k << 8)) rv[k] = -INFINITY;
        __syncthreads();
    }
}

__global__ __launch_bounds__(256) void cumsumA_kernel(
        const float* __restrict__ V, float* __restrict__ chunkSums) {
    int blk = blockIdx.x;
    int c = blk & 15;
    int bh = blk >> 4;
    int h = bh & (NH - 1);
    int b = bh >> 3;
    int g = threadIdx.x >> 6, d = threadIdx.x & 63;

    const size_t rstride = (size_t)NH * ND;
    size_t vbase = (size_t)b * LSEQ * rstride + (size_t)h * ND + d;

    int l0 = c * 256 + g * 64;
    float s = 0.0f;
    for (int l = l0; l < l0 + 64; ++l) s += V[vbase + (size_t)l * rstride];

    __shared__ float part[4][ND];
    part[g][d] = s;
    __syncthreads();
    if (threadIdx.x < ND)
        chunkSums[(size_t)blk * ND + d] =
            part[0][d] + part[1][d] + part[2][d] + part[3][d];
}

__global__ __launch_bounds__(256) void cumsumC_kernel(
        const float* __restrict__ V, const float* __restrict__ chunkSums,
        float* __restrict__ out) {
    int blk = blockIdx.x;
    int c = blk & 15;
    int bh = blk >> 4;
    int h = bh & (NH - 1);
    int b = bh >> 3;
    int g = threadIdx.x >> 6, d = threadIdx.x & 63;

    const size_t rstride = (size_t)NH * ND;
    size_t vbase = (size_t)b * LSEQ * rstride + (size_t)h * ND + d;

    float run = 0.0f;
    for (int cc = 0; cc < c; ++cc)
        run += chunkSums[((size_t)bh * 16 + cc) * ND + d];

    int l0 = c * 256 + g * 64;
    float s = 0.0f;
    for (int l = l0; l < l0 + 64; ++l) s += V[vbase + (size_t)l * rstride];
    __shared__ float part[4][ND];
    part[g][d] = s;
    __syncthreads();
    for (int gg = 0; gg < g; ++gg) run += part[gg][d];

    size_t obase = (size_t)bh * LSEQ * ND + d;
    for (int l = l0; l < l0 + 64; ++l) {
        run += V[vbase + (size_t)l * rstride];
        out[obase + (size_t)l * ND] = run;
    }
}

__global__ __launch_bounds__(256, 1) void attn_partial_kernel(
        const float* __restrict__ Q, const float* __restrict__ K,
        const float* __restrict__ V, const int* __restrict__ Mtop,
        float* __restrict__ part) {
    int bh = blockIdx.x >> 4;
    int c  = blockIdx.x & 15;
    int b = bh >> 3, h = bh & 7;
    int t = threadIdx.x;
    int w = t >> 6, lane = t & 63;
    int jj = lane >> 4, dq = lane & 15;

    __shared__ float Qs[NTOP * ND];
    __shared__ int   posS[NTOP];
    __shared__ float Vs[64][68];
    __shared__ float Pw[4][64];

    size_t base = ((size_t)b * LSEQ * NH + h) * ND;

    if (t < NTOP) posS[t] = Mtop[bh * NTOP + t];
    __syncthreads();
    for (int idx = t; idx < NTOP * 16; idx += 256) {
        int u = idx >> 4, cg = idx & 15;
        f32x4 v = *reinterpret_cast<const f32x4*>(
            Q + base + (size_t)posS[u] * (NH * ND) + cg * 4);
        *reinterpret_cast<f32x4*>(&Qs[u * ND + cg * 4]) = v;
    }

    f32x4 o[12];
    float mreg[12], sreg[12];
    #pragma unroll
    for (int qi = 0; qi < 12; ++qi) {
        o[qi] = 0.0f; mreg[qi] = -INFINITY; sreg[qi] = 0.0f;
    }

    for (int tt = 0; tt < ACH / 64; ++tt) {
        int tile0 = c * ACH + tt * 64;
        __syncthreads();
        #pragma unroll
        for (int i = 0; i < 4; ++i) {
            int flat = i * 256 + t;
            int r = flat >> 4, cg = flat & 15;
            f32x4 v = *reinterpret_cast<const f32x4*>(
                V + base + (size_t)(tile0 + r) * (NH * ND) + cg * 4);
            *reinterpret_cast<f32x4*>(&Vs[r][cg * 4]) = v;
        }
        __syncthreads();

        f32x4 kreg[16];
        #pragma unroll
        for (int i = 0; i < 16; ++i)
            kreg[i] = *reinterpret_cast<const f32x4*>(
                K + base + (size_t)(tile0 + lane) * (NH * ND) + i * 4);

        #pragma unroll
        for (int qi = 0; qi < 12; ++qi) {
            int u = w + 4 * qi;
            if (u >= NTOP) continue;
            int pu = posS[u];
            if (pu < tile0) continue;

            float a0 = 0, a1 = 0, a2 = 0, a3 = 0;
            #pragma unroll
            for (int di = 0; di < 16; ++di) {
                f32x4 qv = *reinterpret_cast<const f32x4*>(&Qs[u * ND + di * 4]);
                a0 = fmaf(qv.x, kreg[di].x, a0);
                a1 = fmaf(qv.y, kreg[di].y, a1);
                a2 = fmaf(qv.z, kreg[di].z, a2);
                a3 = fmaf(qv.w, kreg[di].w, a3);
            }
            float sc = ((a0 + a1) + (a2 + a3)) * 0.125f;
            if (tile0 + lane > pu) sc = -INFINITY;

            float tmax = sc;
            #pragma unroll
            for (int off = 1; off < 64; off <<= 1)
                tmax = fmaxf(tmax, __shfl_xor(tmax, off, 64));
            float mold = mreg[qi];
            float mnew = fmaxf(mold, tmax);
            float alpha = __expf(mold - mnew);
            float e = __expf(sc - mnew);
            float esum = e;
            #pragma unroll
            for (int off = 1; off < 64; off <<= 1)
                esum += __shfl_xor(esum, off, 64);
            sreg[qi] = sreg[qi] * alpha + esum;
            mreg[qi] = mnew;
            Pw[w][lane] = e;
            o[qi] *= alpha;
            #pragma unroll
            for (int i = 0; i < 16; ++i) {
                float pe = Pw[w][i * 4 + jj];
                f32x4 vv = *reinterpret_cast<const f32x4*>(&Vs[i * 4 + jj][dq * 4]);
                o[qi] += vv * pe;
            }
        }
    }

    #pragma unroll
    for (int qi = 0; qi < 12; ++qi) {
        int u = w + 4 * qi;
        if (u >= NTOP) continue;
        if (posS[u] < c * ACH) continue;
        f32x4 oo = o[qi];
        #pragma unroll
        for (int off = 16; off <= 32; off <<= 1) {
            oo.x += __shfl_xor(oo.x, off, 64);
            oo.y += __shfl_xor(oo.y, off, 64);
            oo.z += __shfl_xor(oo.z, off, 64);
            oo.w += __shfl_xor(oo.w, off, 64);
        }
        size_t pb = ((size_t)(bh * NTOP + u) * NCH + c) * 72;
        if (lane < 16)
            *reinterpret_cast<f32x4*>(&part[pb + 4 + dq * 4]) = oo;
        if (lane == 0) { part[pb] = mreg[qi]; part[pb + 1] = sreg[qi]; }
    }
}

__global__ __launch_bounds__(256) void attn_merge_kernel(
        const float* __restrict__ part, const int* __restrict__ Mtop,
        float* __restrict__ ctx) {
    int j = blockIdx.x * 4 + (threadIdx.x >> 6);
    int lane = threadIdx.x & 63;
    int bh = j / NTOP, u = j - bh * NTOP;
    int pos = Mtop[bh * NTOP + u];
    int cmax = pos >> 8;
    size_t pb0 = (size_t)(bh * NTOP + u) * NCH * 72;
    float m = -INFINITY;
    for (int cc = 0; cc <= cmax; ++cc)
        m = fmaxf(m, part[pb0 + (size_t)cc * 72]);
    float S = 0.0f, oacc = 0.0f;
    for (int cc = 0; cc <= cmax; ++cc) {
        float mc = part[pb0 + (size_t)cc * 72];
        float sc = part[pb0 + (size_t)cc * 72 + 1];
        float wgt = __expf(mc - m);
        S = fmaf(sc, wgt, S);
        oacc = fmaf(part[pb0 + (size_t)cc * 72 + 4 + lane], wgt, oacc);
    }
    ctx[(size_t)j * ND + lane] = oacc / S;
}

__global__ __launch_bounds__(256) void scatter_kernel(
        const float* __restrict__ ctx, const int* __restrict__ Mtop,
        float* __restrict__ out) {
    int j = blockIdx.x * 4 + (threadIdx.x >> 6);
    int lane = threadIdx.x & 63;
    int bh = j / NTOP, u = j - bh * NTOP;
    int pos = Mtop[bh * NTOP + u];
    out[((size_t)bh * LSEQ + pos) * ND + lane] = ctx[(size_t)j * ND + lane];
}

#define TJ 64
__global__ __launch_bounds__(256) void attn_rows_kernel(
        const float* __restrict__ Q,
        const float* __restrict__ K,
        const float* __restrict__ V,
        const int* __restrict__ Mtop,
        float* __restrict__ out) {
    int x = blockIdx.x;
    int xcd = x & 7;
    int slot = x >> 3;
    int grp = slot / NTOP;
    int u = slot % NTOP;
    int bh = grp * 8 + xcd;
    int h = bh & (NH - 1);
    int b = bh >> 3;
    int pos = Mtop[bh * NTOP + u];
    int n = pos + 1;
    int t = threadIdx.x;
    int r = t >> 2, qt = t & 3;

    __shared__ float Ks[TJ][65];
    __shared__ float Vs[TJ][65];
    __shared__ float red[256];

    const size_t rstride = (size_t)NH * ND;
    size_t base = (size_t)b * LSEQ * rstride + (size_t)h * ND;

    float qreg[16];
    const float* qrow = Q + base + (size_t)pos * rstride + qt * 16;
    #pragma unroll
    for (int i = 0; i < 16; i += 4) {
        float4 v4 = *reinterpret_cast<const float4*>(qrow + i);
        qreg[i] = v4.x; qreg[i + 1] = v4.y; qreg[i + 2] = v4.z; qreg[i + 3] = v4.w;
    }

    float m = -INFINITY, s = 0.0f;
    float o[16];
    #pragma unroll
    for (int dd = 0; dd < 16; ++dd) o[dd] = 0.0f;

    int ntiles = (n + TJ - 1) / TJ;
    for (int tt = 0; tt < ntiles; ++tt) {
        int j0 = tt * TJ;
        __syncthreads();
        #pragma unroll
        for (int i = 0; i < 4; ++i) {
            int u16 = t + i * 256;
            int rr = u16 >> 4, cc = u16 & 15;
            int j = j0 + rr;
            int jc = (j < n) ? j : (n - 1);
            const float* rowk = K + base + (size_t)jc * rstride;
            float4 kv = *reinterpret_cast<const float4*>(rowk + cc * 4);
            Ks[rr][cc * 4 + 0] = kv.x; Ks[rr][cc * 4 + 1] = kv.y;
            Ks[rr][cc * 4 + 2] = kv.z; Ks[rr][cc * 4 + 3] = kv.w;
            const float* rowv = V + base + (size_t)jc * rstride;
            float4 vv = *reinterpret_cast<const float4*>(rowv + cc * 4);
            Vs[rr][cc * 4 + 0] = vv.x; Vs[rr][cc * 4 + 1] = vv.y;
            Vs[rr][cc * 4 + 2] = vv.z; Vs[rr][cc * 4 + 3] = vv.w;
        }
        __syncthreads();

        int j = j0 + r;
        float acc = 0.0f;
        #pragma unroll
        for (int dd = 0; dd < 16; ++dd)
            acc = fmaf(qreg[dd], Ks[r][qt * 16 + dd], acc);
        acc += __shfl_xor(acc, 1, 64);
        acc += __shfl_xor(acc, 2, 64);

        if (j < n) {
            float sc = acc * 0.125f;
            if (sc > m) {
                float alpha = __expf(m - sc);
                s *= alpha;
                #pragma unroll
                for (int dd = 0; dd < 16; ++dd) o[dd] *= alpha;
                m = sc;
            }
            float e = __expf(sc - m);
            s += e;
            #pragma unroll
            for (int dd = 0; dd < 16; ++dd)
                o[dd] = fmaf(e, Vs[r][qt * 16 + dd], o[dd]);
        }
    }
    __syncthreads();

    red[t] = m; __syncthreads();
    for (int sft = 128; sft; sft >>= 1) {
        if (t < sft) red[t] = fmaxf(red[t], red[t + sft]);
        __syncthreads();
    }
    float mstar = red[0]; __syncthreads();
    float a = __expf(m - mstar);

    red[t] = s * a; __syncthreads();
    for (int sft = 128; sft; sft >>= 1) {
        if (t < sft) red[t] += red[t + sft];
        __syncthreads();
    }
    float S = red[0]; __syncthreads();

    float* OB = &Ks[0][0];
    #pragma unroll
    for (int dd = 0; dd < 16; ++dd) OB[t * 16 + dd] = o[dd] * a;
    __syncthreads();

    if (t < ND) {
        int qtt = t >> 4, dd = t & 15;
        float tot = 0.0f;
        for (int k = 0; k < 64; ++k) tot += OB[(4 * k + qtt) * 16 + dd];
        out[((size_t)bh * LSEQ + pos) * ND + t] = tot / S;
    }
}

// ---------------------------------------------------------------------------
extern "C" void kernel_launch(void* const* d_in, const int* in_sizes, int n_in,
                              void* d_out, int out_size, void* d_ws, size_t ws_size,
                              hipStream_t stream) {
    const float* Q = (const float*)d_in[0];
    const float* K = (const float*)d_in[1];
    const float* V = (const float*)d_in[2];
    const int* idxS = (const int*)d_in[3];
    float* out = (float*)d_out;

    // Fast-tier ws layout:
    //   0        cntM[32] | 128 cntA[32] | 256 cnt2[512]      (zeroed by KA)
    //   4096     Mtop (5760 B)
    //   16384    chunkSums (131072)
    //   147456   ctx (368640)
    //   516096   M (524288)
    //   1040384  sortedPack (737280)
    //   1777664  part (6635520)  -> total 8413184
    int*   cnts   = (int*)d_ws;
    int*   MtopF  = (int*)((char*)d_ws + 4096);
    float* chSumF = (float*)((char*)d_ws + 16384);
    float* ctxF   = (float*)((char*)d_ws + 147456);
    float* MF     = (float*)((char*)d_ws + 516096);
    int*   sortF  = (int*)((char*)d_ws + 1040384);
    float* partF  = (float*)((char*)d_ws + 1777664);
    const size_t wsFast = 1777664 + 6635520;

    if (ws_size >= wsFast) {
        // 3-launch fused pipeline.
        fusedA_kernel<<<528, 256, 0, stream>>>(idxS, sortF, V, chSumF, cnts);
        fusedM_kernel<<<256, 512, 0, stream>>>(Q, K, sortF, MF, MtopF, cnts, 1);
        fusedC_kernel<<<1024, 256, 0, stream>>>(Q, K, V, MtopF, partF, chSumF,
                                                ctxF, out, cnts + 32, cnts + 64);
        return;
    }

    // --- Fallback tiers (round-7 scheme, d_out scratch) ---
    float* Mbuf = (float*)d_out;
    int*   sortedPack = (int*)((char*)d_out + (1 << 20));
    float* part = (float*)((char*)d_out + (2 << 20));
    int*   Mtop = (int*)d_ws;
    float* chunkSums = (float*)((char*)d_ws + 8192);
    float* ctx = (float*)((char*)d_ws + 8192 + 131072);
    size_t wsMid = 8192 + 131072 + (size_t)NB * NH * NTOP * ND * 4;

    prep_kernel<<<LSEQ / 256, 256, 0, stream>>>(idxS, sortedPack);
    fusedM_kernel<<<256, 512, 0, stream>>>(Q, K, sortedPack, Mbuf, Mtop, Mtop, 0);
    topk_kernel<<<NB * NH, 256, 0, stream>>>(Mbuf, Mtop);

    if (ws_size >= wsMid) {
        attn_partial_kernel<<<NB * NH * NCH, 256, 0, stream>>>(Q, K, V, Mtop, part);
        attn_merge_kernel<<<NB * NH * NTOP / 4, 256, 0, stream>>>(part, Mtop, ctx);
        cumsumA_kernel<<<NB * NH * 16, 256, 0, stream>>>(V, chunkSums);
        cumsumC_kernel<<<NB * NH * 16, 256, 0, stream>>>(V, chunkSums, out);
        scatter_kernel<<<NB * NH * NTOP / 4, 256, 0, stream>>>(ctx, Mtop, out);
    } else {
        cumsumA_kernel<<<NB * NH * 16, 256, 0, stream>>>(V, chunkSums);
        cumsumC_kernel<<<NB * NH * 16, 256, 0, stream>>>(V, chunkSums, out);
        attn_rows_kernel<<<NB * NH * NTOP, 256, 0, stream>>>(Q, K, V, Mtop, out);
    }
}

// Round 12
// 424.332 us; speedup vs baseline: 1.5484x; 1.5484x over previous
//
#include <hip/hip_runtime.h>

// Problem constants (B, L, H, D) = (4, 4096, 8, 64), FACTOR=5
#define NB 4
#define LSEQ 4096
#define NH 8
#define ND 64
#define NSAMP 45
#define NTOP 45
#define ACH 256            // keys per attention chunk
#define NCH (LSEQ / ACH)   // 16 chunks

typedef float f32x4 __attribute__((ext_vector_type(4)));

// ===========================================================================
// r17: FENCE-FREE PIPELINE. r15/r16 post-mortem: fusedC (attn+cumsumC with
// device-scope fences + atomics) ran 365-380us vs <=160us unfused — 1024
// blocks of __threadfence() on non-coherent XCD L2s poisons the memory
// system. Kernel boundaries ARE the cheap sync. Keep only fence-free fusion:
//   1. fusedA   = prep U cumsumA          (independent work, grid union)
//   2. compute_M (r7 body verbatim, 107us; M bit-identical)
//   3. topk     (r7 verbatim; selection frozen)
//   4. attn_partial (r11 verbatim)
//   5. attn_merge   (verbatim)
//   6. cumsumC+scatter fused: ctx complete before launch (stream order);
//      each (bh,c) block scatters rows of ITS OWN chunk after its own
//      cumsum writes + __syncthreads() — same-block ordering, no fence.
// 6 launches, zero atomics/fences. Fallback: cumsumCS(noScatter)+attn_rows.
// ===========================================================================

// ---------------------------------------------------------------------------
// K1 fusedA: blocks 0..15 = prep (bucket-sort (idx,s) by chunk; r10
// semantics); blocks 16..527 = cumsumA (per-chunk V sums).
// ---------------------------------------------------------------------------
__global__ __launch_bounds__(256) void fusedA_kernel(
        const int* __restrict__ idxS, int* __restrict__ sortedPack,
        const float* __restrict__ V, float* __restrict__ chunkSums) {
    int blk = blockIdx.x;
    int t = threadIdx.x;
    __shared__ int cnt[256][17];
    __shared__ float part[4][ND];

    if (blk < 16) {
        int l = blk * 256 + t;
        const int* is = idxS + (size_t)l * NSAMP;
        #pragma unroll
        for (int c = 0; c < 16; ++c) cnt[t][c] = 0;
        for (int s = 0; s < NSAMP; ++s) cnt[t][is[s] >> 8] += 1;
        int run = 0;
        #pragma unroll
        for (int c = 0; c < 16; ++c) { int v = cnt[t][c]; cnt[t][c] = run; run += v; }
        for (int s = 0; s < NSAMP; ++s) {
            int idx = is[s];
            int pos = cnt[t][idx >> 8]++;
            sortedPack[(size_t)l * NSAMP + pos] = (idx << 8) | s;
        }
    } else {
        int blk2 = blk - 16;
        int c = blk2 & 15;
        int bh = blk2 >> 4;
        int h = bh & (NH - 1);
        int b = bh >> 3;
        int g = t >> 6, d = t & 63;

        const size_t rstride = (size_t)NH * ND;
        size_t vbase = (size_t)b * LSEQ * rstride + (size_t)h * ND + d;

        int l0 = c * 256 + g * 64;
        float s = 0.0f;
        for (int l = l0; l < l0 + 64; ++l) s += V[vbase + (size_t)l * rstride];

        part[g][d] = s;
        __syncthreads();
        if (t < ND)
            chunkSums[(size_t)blk2 * ND + d] =
                part[0][d] + part[1][d] + part[2][d] + part[3][d];
    }
}

// ---------------------------------------------------------------------------
// K2 compute_M: ROUND-7 BODY VERBATIM (107us best). LDS-staged K chunks,
// Plds parked dots, ORIGINAL-s-order fold -> M bit-identical -> selection
// frozen. 512 threads (2 waves/SIMD), grid 256, XCD-pinned K stream.
// ---------------------------------------------------------------------------
__global__ __launch_bounds__(512, 1) void compute_M_kernel(
        const float* __restrict__ Q,
        const float* __restrict__ K,
        const int* __restrict__ sortedPack,
        float* __restrict__ Mout) {
    int xcd = blockIdx.x & 7;
    int sub = blockIdx.x >> 3;
    int bh  = (xcd << 2) | (sub & 3);      // 4 bh per XCD -> 4MB L2 K stream
    int lt  = sub >> 2;                    // 0..7 (512-l tile)
    int b = bh >> 3, h = bh & 7;
    int t = threadIdx.x;                   // 0..511
    int l0 = (lt << 9) + t;

    __shared__ float Ks[256 * 68];
    __shared__ float Plds[512 * 45];

    f32x4 qa[16];
    {
        const f32x4* qp0 = reinterpret_cast<const f32x4*>(
            Q + (((size_t)b * LSEQ + l0) * NH + h) * ND);
        #pragma unroll
        for (int i = 0; i < 16; ++i) qa[i] = __builtin_nontemporal_load(qp0 + i);
    }

    auto dotQK = [&](const f32x4 (&q4)[16], const float* kr) -> float {
        const f32x4* k4 = reinterpret_cast<const f32x4*>(kr);
        float w[32];
        #pragma unroll
        for (int i = 0; i < 8; ++i) {
            f32x4 a = q4[i], bb = k4[i], c = q4[i + 8], d4 = k4[i + 8];
            w[4 * i + 0] = __fadd_rn(__fmul_rn(a.x, bb.x), __fmul_rn(c.x, d4.x));
            w[4 * i + 1] = __fadd_rn(__fmul_rn(a.y, bb.y), __fmul_rn(c.y, d4.y));
            w[4 * i + 2] = __fadd_rn(__fmul_rn(a.z, bb.z), __fmul_rn(c.z, d4.z));
            w[4 * i + 3] = __fadd_rn(__fmul_rn(a.w, bb.w), __fmul_rn(c.w, d4.w));
        }
        #pragma unroll
        for (int off = 16; off; off >>= 1) {
            #pragma unroll
            for (int i = 0; i < off; ++i) w[i] = __fadd_rn(w[i], w[i + off]);
        }
        return w[0];
    };

    const int* sp0 = sortedPack + (size_t)l0 * NSAMP;
    int ptr0 = 0;
    int pk0 = sp0[0];

    size_t kbh = ((size_t)b * LSEQ * NH + h) * ND;

    for (int c = 0; c < 16; ++c) {
        #pragma unroll
        for (int i = 0; i < 8; ++i) {
            int flat = i * 512 + t;
            int row = flat >> 4, col = flat & 15;
            f32x4 v = *reinterpret_cast<const f32x4*>(
                K + kbh + (size_t)(c * 256 + row) * (NH * ND) + col * 4);
            *reinterpret_cast<f32x4*>(&Ks[row * 68 + col * 4]) = v;
        }
        __syncthreads();

        while ((pk0 >> 16) == c) {
            int r = (pk0 >> 8) & 255;
            int s = pk0 & 255;
            Plds[t * 45 + s] = dotQK(qa, &Ks[r * 68]);
            ++ptr0;
            pk0 = (ptr0 < NSAMP) ? sp0[ptr0] : 0x7fffffff;
        }
        __syncthreads();
    }

    {
        float maxv = -INFINITY, sumv = 0.0f;
        for (int s = 0; s < NSAMP; ++s) {
            float v = Plds[t * 45 + s];
            maxv = fmaxf(maxv, v);
            sumv = __fadd_rn(sumv, v);
        }
        Mout[(size_t)bh * LSEQ + l0] = maxv - sumv * (1.0f / (float)LSEQ);
    }
}

// ---------------------------------------------------------------------------
// K3 topk: top-45 per (b,h). UNCHANGED (selection semantics frozen).
// ---------------------------------------------------------------------------
__global__ __launch_bounds__(256) void topk_kernel(
        const float* __restrict__ M, int* __restrict__ Mtop) {
    int bh = blockIdx.x;
    int t = threadIdx.x;
    int wave = t >> 6, lane = t & 63;
    const float* m = M + (size_t)bh * LSEQ;

    float rv[16];
    #pragma unroll
    for (int k = 0; k < 16; ++k) rv[k] = m[t + (k << 8)];

    __shared__ float wv[4];
    __shared__ int   wi[4];
    __shared__ int   winIdx;

    for (int iter = 0; iter < NTOP; ++iter) {
        float bv = -INFINITY; int bi = 0x7fffffff;
        #pragma unroll
        for (int k = 0; k < 16; ++k) {
            float v = rv[k];
            if (v > bv) { bv = v; bi = t + (k << 8); }
        }
        #pragma unroll
        for (int off = 1; off < 64; off <<= 1) {
            float ov = __shfl_xor(bv, off, 64);
            int   oi = __shfl_xor(bi, off, 64);
            if (ov > bv || (ov == bv && oi < bi)) { bv = ov; bi = oi; }
        }
        if (lane == 0) { wv[wave] = bv; wi[wave] = bi; }
        __syncthreads();
        if (t == 0) {
            float cv = wv[0]; int ci = wi[0];
            for (int ww = 1; ww < 4; ++ww) {
                if (wv[ww] > cv || (wv[ww] == cv && wi[ww] < ci)) { cv = wv[ww]; ci = wi[ww]; }
            }
            winIdx = ci;
            Mtop[bh * NTOP + iter] = ci;
        }
        __syncthreads();
        int widx = winIdx;
        #pragma unroll
        for (int k = 0; k < 16; ++k)
            if (widx == t + (k << 8)) rv[k] = -INFINITY;
        __syncthreads();
    }
}

// ---------------------------------------------------------------------------
// K4 attn_partial: flash split-K attention (r11 body). UNCHANGED.
// ---------------------------------------------------------------------------
__global__ __launch_bounds__(256, 1) void attn_partial_kernel(
        const float* __restrict__ Q, const float* __restrict__ K,
        const float* __restrict__ V, const int* __restrict__ Mtop,
        float* __restrict__ part) {
    int bh = blockIdx.x >> 4;
    int c  = blockIdx.x & 15;
    int b = bh >> 3, h = bh & 7;
    int t = threadIdx.x;
    int w = t >> 6, lane = t & 63;
    int jj = lane >> 4, dq = lane & 15;

    __shared__ float Qs[NTOP * ND];
    __shared__ int   posS[NTOP];
    __shared__ float Vs[64][68];
    __shared__ float Pw[4][64];

    size_t base = ((size_t)b * LSEQ * NH + h) * ND;

    if (t < NTOP) posS[t] = Mtop[bh * NTOP + t];
    __syncthreads();
    for (int idx = t; idx < NTOP * 16; idx += 256) {
        int u = idx >> 4, cg = idx & 15;
        f32x4 v = *reinterpret_cast<const f32x4*>(
            Q + base + (size_t)posS[u] * (NH * ND) + cg * 4);
        *reinterpret_cast<f32x4*>(&Qs[u * ND + cg * 4]) = v;
    }

    f32x4 o[12];
    float mreg[12], sreg[12];
    #pragma unroll
    for (int qi = 0; qi < 12; ++qi) {
        o[qi] = 0.0f; mreg[qi] = -INFINITY; sreg[qi] = 0.0f;
    }

    for (int tt = 0; tt < ACH / 64; ++tt) {
        int tile0 = c * ACH + tt * 64;
        __syncthreads();
        #pragma unroll
        for (int i = 0; i < 4; ++i) {
            int flat = i * 256 + t;
            int r = flat >> 4, cg = flat & 15;
            f32x4 v = *reinterpret_cast<const f32x4*>(
                V + base + (size_t)(tile0 + r) * (NH * ND) + cg * 4);
            *reinterpret_cast<f32x4*>(&Vs[r][cg * 4]) = v;
        }
        __syncthreads();

        f32x4 kreg[16];
        #pragma unroll
        for (int i = 0; i < 16; ++i)
            kreg[i] = *reinterpret_cast<const f32x4*>(
                K + base + (size_t)(tile0 + lane) * (NH * ND) + i * 4);

        #pragma unroll
        for (int qi = 0; qi < 12; ++qi) {
            int u = w + 4 * qi;
            if (u >= NTOP) continue;
            int pu = posS[u];
            if (pu < tile0) continue;

            float a0 = 0, a1 = 0, a2 = 0, a3 = 0;
            #pragma unroll
            for (int di = 0; di < 16; ++di) {
                f32x4 qv = *reinterpret_cast<const f32x4*>(&Qs[u * ND + di * 4]);
                a0 = fmaf(qv.x, kreg[di].x, a0);
                a1 = fmaf(qv.y, kreg[di].y, a1);
                a2 = fmaf(qv.z, kreg[di].z, a2);
                a3 = fmaf(qv.w, kreg[di].w, a3);
            }
            float sc = ((a0 + a1) + (a2 + a3)) * 0.125f;
            if (tile0 + lane > pu) sc = -INFINITY;

            float tmax = sc;
            #pragma unroll
            for (int off = 1; off < 64; off <<= 1)
                tmax = fmaxf(tmax, __shfl_xor(tmax, off, 64));
            float mold = mreg[qi];
            float mnew = fmaxf(mold, tmax);
            float alpha = __expf(mold - mnew);
            float e = __expf(sc - mnew);
            float esum = e;
            #pragma unroll
            for (int off = 1; off < 64; off <<= 1)
                esum += __shfl_xor(esum, off, 64);
            sreg[qi] = sreg[qi] * alpha + esum;
            mreg[qi] = mnew;
            Pw[w][lane] = e;
            o[qi] *= alpha;
            #pragma unroll
            for (int i = 0; i < 16; ++i) {
                float pe = Pw[w][i * 4 + jj];
                f32x4 vv = *reinterpret_cast<const f32x4*>(&Vs[i * 4 + jj][dq * 4]);
                o[qi] += vv * pe;
            }
        }
    }

    #pragma unroll
    for (int qi = 0; qi < 12; ++qi) {
        int u = w + 4 * qi;
        if (u >= NTOP) continue;
        if (posS[u] < c * ACH) continue;
        f32x4 oo = o[qi];
        #pragma unroll
        for (int off = 16; off <= 32; off <<= 1) {
            oo.x += __shfl_xor(oo.x, off, 64);
            oo.y += __shfl_xor(oo.y, off, 64);
            oo.z += __shfl_xor(oo.z, off, 64);
            oo.w += __shfl_xor(oo.w, off, 64);
        }
        size_t pb = ((size_t)(bh * NTOP + u) * NCH + c) * 72;
        if (lane < 16)
            *reinterpret_cast<f32x4*>(&part[pb + 4 + dq * 4]) = oo;
        if (lane == 0) { part[pb] = mreg[qi]; part[pb + 1] = sreg[qi]; }
    }
}

// ---------------------------------------------------------------------------
// K5 attn_merge: merge chunk partials -> compact ctx. UNCHANGED.
// ---------------------------------------------------------------------------
__global__ __launch_bounds__(256) void attn_merge_kernel(
        const float* __restrict__ part, const int* __restrict__ Mtop,
        float* __restrict__ ctx) {
    int j = blockIdx.x * 4 + (threadIdx.x >> 6);
    int lane = threadIdx.x & 63;
    int bh = j / NTOP, u = j - bh * NTOP;
    int pos = Mtop[bh * NTOP + u];
    int cmax = pos >> 8;
    size_t pb0 = (size_t)(bh * NTOP + u) * NCH * 72;
    float m = -INFINITY;
    for (int cc = 0; cc <= cmax; ++cc)
        m = fmaxf(m, part[pb0 + (size_t)cc * 72]);
    float S = 0.0f, oacc = 0.0f;
    for (int cc = 0; cc <= cmax; ++cc) {
        float mc = part[pb0 + (size_t)cc * 72];
        float sc = part[pb0 + (size_t)cc * 72 + 1];
        float wgt = __expf(mc - m);
        S = fmaf(sc, wgt, S);
        oacc = fmaf(part[pb0 + (size_t)cc * 72 + 4 + lane], wgt, oacc);
    }
    ctx[(size_t)j * ND + lane] = oacc / S;
}

// ---------------------------------------------------------------------------
// K6 cumsumC+scatter: rescan chunk with exclusive prefix, write out; then
// (doScatter) overwrite the attention rows whose pos falls in THIS block's
// chunk with ctx rows. ctx is complete before this kernel launches (stream
// order after attn_merge); within the block, __syncthreads() orders the
// cumsum writes before the scatter overwrites (same CU, no fence needed).
// ---------------------------------------------------------------------------
__global__ __launch_bounds__(256) void cumsumCS_kernel(
        const float* __restrict__ V, const float* __restrict__ chunkSums,
        const int* __restrict__ Mtop, const float* __restrict__ ctx,
        float* __restrict__ out, int doScatter) {
    int blk = blockIdx.x;
    int c = blk & 15;
    int bh = blk >> 4;
    int h = bh & (NH - 1);
    int b = bh >> 3;
    int g = threadIdx.x >> 6, d = threadIdx.x & 63;
    int t = threadIdx.x;

    const size_t rstride = (size_t)NH * ND;
    size_t vbase = (size_t)b * LSEQ * rstride + (size_t)h * ND + d;

    float run = 0.0f;
    for (int cc = 0; cc < c; ++cc)
        run += chunkSums[((size_t)bh * 16 + cc) * ND + d];

    int l0 = c * 256 + g * 64;
    float s = 0.0f;
    for (int l = l0; l < l0 + 64; ++l) s += V[vbase + (size_t)l * rstride];
    __shared__ float part[4][ND];
    part[g][d] = s;
    __syncthreads();
    for (int gg = 0; gg < g; ++gg) run += part[gg][d];

    size_t obase = (size_t)bh * LSEQ * ND + d;
    for (int l = l0; l < l0 + 64; ++l) {
        run += V[vbase + (size_t)l * rstride];
        out[obase + (size_t)l * ND] = run;
    }

    if (!doScatter) return;
    __syncthreads();   // all cumsum writes of this block done (barrier drains vmcnt)
    for (int idx = t; idx < NTOP * ND; idx += 256) {
        int u = idx >> 6, d2 = idx & 63;
        int pos = Mtop[bh * NTOP + u];
        if ((pos >> 8) == c)
            out[((size_t)bh * LSEQ + pos) * ND + d2] =
                ctx[(size_t)(bh * NTOP + u) * ND + d2];
    }
}

// ---------------------------------------------------------------------------
// Fallback: per-(bh,u) flash attention (r6). Used only if ws too small.
// ---------------------------------------------------------------------------
#define TJ 64
__global__ __launch_bounds__(256) void attn_rows_kernel(
        const float* __restrict__ Q,
        const float* __restrict__ K,
        const float* __restrict__ V,
        const int* __restrict__ Mtop,
        float* __restrict__ out) {
    int x = blockIdx.x;
    int xcd = x & 7;
    int slot = x >> 3;
    int grp = slot / NTOP;
    int u = slot % NTOP;
    int bh = grp * 8 + xcd;
    int h = bh & (NH - 1);
    int b = bh >> 3;
    int pos = Mtop[bh * NTOP + u];
    int n = pos + 1;
    int t = threadIdx.x;
    int r = t >> 2, qt = t & 3;

    __shared__ float Ks[TJ][65];
    __shared__ float Vs[TJ][65];
    __shared__ float red[256];

    const size_t rstride = (size_t)NH * ND;
    size_t base = (size_t)b * LSEQ * rstride + (size_t)h * ND;

    float qreg[16];
    const float* qrow = Q + base + (size_t)pos * rstride + qt * 16;
    #pragma unroll
    for (int i = 0; i < 16; i += 4) {
        float4 v4 = *reinterpret_cast<const float4*>(qrow + i);
        qreg[i] = v4.x; qreg[i + 1] = v4.y; qreg[i + 2] = v4.z; qreg[i + 3] = v4.w;
    }

    float m = -INFINITY, s = 0.0f;
    float o[16];
    #pragma unroll
    for (int dd = 0; dd < 16; ++dd) o[dd] = 0.0f;

    int ntiles = (n + TJ - 1) / TJ;
    for (int tt = 0; tt < ntiles; ++tt) {
        int j0 = tt * TJ;
        __syncthreads();
        #pragma unroll
        for (int i = 0; i < 4; ++i) {
            int u16 = t + i * 256;
            int rr = u16 >> 4, cc = u16 & 15;
            int j = j0 + rr;
            int jc = (j < n) ? j : (n - 1);
            const float* rowk = K + base + (size_t)jc * rstride;
            float4 kv = *reinterpret_cast<const float4*>(rowk + cc * 4);
            Ks[rr][cc * 4 + 0] = kv.x; Ks[rr][cc * 4 + 1] = kv.y;
            Ks[rr][cc * 4 + 2] = kv.z; Ks[rr][cc * 4 + 3] = kv.w;
            const float* rowv = V + base + (size_t)jc * rstride;
            float4 vv = *reinterpret_cast<const float4*>(rowv + cc * 4);
            Vs[rr][cc * 4 + 0] = vv.x; Vs[rr][cc * 4 + 1] = vv.y;
            Vs[rr][cc * 4 + 2] = vv.z; Vs[rr][cc * 4 + 3] = vv.w;
        }
        __syncthreads();

        int j = j0 + r;
        float acc = 0.0f;
        #pragma unroll
        for (int dd = 0; dd < 16; ++dd)
            acc = fmaf(qreg[dd], Ks[r][qt * 16 + dd], acc);
        acc += __shfl_xor(acc, 1, 64);
        acc += __shfl_xor(acc, 2, 64);

        if (j < n) {
            float sc = acc * 0.125f;
            if (sc > m) {
                float alpha = __expf(m - sc);
                s *= alpha;
                #pragma unroll
                for (int dd = 0; dd < 16; ++dd) o[dd] *= alpha;
                m = sc;
            }
            float e = __expf(sc - m);
            s += e;
            #pragma unroll
            for (int dd = 0; dd < 16; ++dd)
                o[dd] = fmaf(e, Vs[r][qt * 16 + dd], o[dd]);
        }
    }
    __syncthreads();

    red[t] = m; __syncthreads();
    for (int sft = 128; sft; sft >>= 1) {
        if (t < sft) red[t] = fmaxf(red[t], red[t + sft]);
        __syncthreads();
    }
    float mstar = red[0]; __syncthreads();
    float a = __expf(m - mstar);

    red[t] = s * a; __syncthreads();
    for (int sft = 128; sft; sft >>= 1) {
        if (t < sft) red[t] += red[t + sft];
        __syncthreads();
    }
    float S = red[0]; __syncthreads();

    float* OB = &Ks[0][0];
    #pragma unroll
    for (int dd = 0; dd < 16; ++dd) OB[t * 16 + dd] = o[dd] * a;
    __syncthreads();

    if (t < ND) {
        int qtt = t >> 4, dd = t & 15;
        float tot = 0.0f;
        for (int k = 0; k < 64; ++k) tot += OB[(4 * k + qtt) * 16 + dd];
        out[((size_t)bh * LSEQ + pos) * ND + t] = tot / S;
    }
}

// ---------------------------------------------------------------------------
extern "C" void kernel_launch(void* const* d_in, const int* in_sizes, int n_in,
                              void* d_out, int out_size, void* d_ws, size_t ws_size,
                              hipStream_t stream) {
    const float* Q = (const float*)d_in[0];
    const float* K = (const float*)d_in[1];
    const float* V = (const float*)d_in[2];
    const int* idxS = (const int*)d_in[3];
    float* out = (float*)d_out;

    // d_out scratch (all consumed before cumsumCS overwrites):
    //   M        @ 0     (512 KB)  -> topk
    //   sorted   @ 1 MB  (737 KB)  -> compute_M
    //   part     @ 2 MB  (6.6 MB)  -> attn_merge
    // ws: Mtop (5760B) @0, chunkSums (128KB) @8192, ctx (360KB) @139264.
    float* Mbuf = (float*)d_out;
    int*   sortedPack = (int*)((char*)d_out + (1 << 20));
    float* part = (float*)((char*)d_out + (2 << 20));
    int*   Mtop = (int*)d_ws;
    float* chunkSums = (float*)((char*)d_ws + 8192);
    float* ctx = (float*)((char*)d_ws + 8192 + 131072);
    size_t wsMid = 8192 + 131072 + (size_t)NB * NH * NTOP * ND * 4;

    fusedA_kernel<<<528, 256, 0, stream>>>(idxS, sortedPack, V, chunkSums);
    compute_M_kernel<<<256, 512, 0, stream>>>(Q, K, sortedPack, Mbuf);
    topk_kernel<<<NB * NH, 256, 0, stream>>>(Mbuf, Mtop);

    if (ws_size >= wsMid) {
        attn_partial_kernel<<<NB * NH * NCH, 256, 0, stream>>>(Q, K, V, Mtop, part);
        attn_merge_kernel<<<NB * NH * NTOP / 4, 256, 0, stream>>>(part, Mtop, ctx);
        cumsumCS_kernel<<<NB * NH * 16, 256, 0, stream>>>(V, chunkSums, Mtop, ctx, out, 1);
    } else {
        cumsumCS_kernel<<<NB * NH * 16, 256, 0, stream>>>(V, chunkSums, Mtop, ctx, out, 0);
        attn_rows_kernel<<<NB * NH * NTOP, 256, 0, stream>>>(Q, K, V, Mtop, out);
    }
}